// Round 4
// baseline (1747.766 us; speedup 1.0000x reference)
//
#include <hip/hip_runtime.h>
#include <hip/hip_bf16.h>
#include <hip/hip_cooperative_groups.h>
#include <stdint.h>

namespace cg = cooperative_groups;

using f32x4  = __attribute__((ext_vector_type(4))) float;
using bf16x8 = __attribute__((ext_vector_type(8))) short;
using bf16x4 = __attribute__((ext_vector_type(4))) short;

#define NB   4
#define NC   128
#define NT   8192
#define TL   64
#define NLAYER 20
#define GROWB 272
#define CONVN (NLAYER * 256 * 256)
#define WOUTN (NLAYER * 128 * 128)

__device__ __forceinline__ short f2b(float f) {
  union { float f; unsigned u; } v; v.f = f;
  unsigned r = v.u + 0x7FFFu + ((v.u >> 16) & 1u);   // RNE
  return (short)(r >> 16);
}

__device__ __forceinline__ f32x4 mfma16(bf16x8 a, bf16x8 b, f32x4 c) {
  return __builtin_amdgcn_mfma_f32_16x16x32_bf16(a, b, c, 0, 0, 0);
}

__device__ __forceinline__ void gl_lds16(const void* g, void* l) {
  __builtin_amdgcn_global_load_lds(
      (const __attribute__((address_space(1))) void*)g,
      (__attribute__((address_space(3))) void*)l, 16, 0, 0);
}

// x [NB][NC][NT] f32 -> xtb bf16 swizzled (256B rows, 16B groups XOR t&7)
__global__ void transpose_in(const float* __restrict__ x, short* __restrict__ xtb) {
  __shared__ float tile[64][65];
  const int t0 = blockIdx.x * 64;
  const int c0 = blockIdx.y * 64;
  const int b  = blockIdx.z;
  const int lane = threadIdx.x & 63;
  const int r4   = threadIdx.x >> 6;
  #pragma unroll
  for (int i = 0; i < 16; ++i) {
    const int cl = i * 4 + r4;
    tile[cl][lane] = x[((size_t)(b * NC + c0 + cl)) * NT + t0 + lane];
  }
  __syncthreads();
  #pragma unroll
  for (int i = 0; i < 16; ++i) {
    const int tr = i * 4 + r4;
    const float v = tile[lane][tr];
    const int t = t0 + tr, c = c0 + lane;
    const size_t rowB = ((size_t)(b * NT + t)) * 256;
    const int ci = (c >> 3) ^ (t & 7);
    *(short*)((char*)xtb + rowB + ci * 16 + (c & 7) * 2) = f2b(v);
  }
}

// pack weights to bf16, fragment-ordered: wcb[l][o][k], k = tap*128 + c
__global__ void pack_weights(const float* __restrict__ w_conv,
                             const float* __restrict__ w_out,
                             short* __restrict__ wcb, short* __restrict__ wob) {
  const int idx = blockIdx.x * 256 + threadIdx.x;
  if (idx < CONVN) {
    const int k = idx & 255, o = (idx >> 8) & 255, lyr = idx >> 16;
    const int tap = k >> 7, c = k & 127;
    wcb[idx] = f2b(w_conv[(((size_t)lyr * 256 + o) * 128 + c) * 2 + tap]);
  } else if (idx < CONVN + WOUTN) {
    const int j = idx - CONVN;
    wob[j] = f2b(w_out[j]);
  }
}

__global__ __launch_bounds__(512, 2)
void wavenet_persistent(const short* __restrict__ wcb,
                        const float* __restrict__ b_conv,
                        const short* __restrict__ wob,
                        const float* __restrict__ b_out,
                        const float* __restrict__ x,
                        short* __restrict__ xb_a,
                        short* __restrict__ xb_b,
                        float* __restrict__ out)
{
  __shared__ char ldsX[4][TL * 256];   // [XC0, XP0, XC1, XP1]
  __shared__ char ldsG[TL * GROWB];

  const int tid = threadIdx.x;
  const int w   = tid >> 6;
  const int l   = tid & 63;
  const int lh  = l & 15;
  const int lq  = l >> 4;
  const int o0  = 16 * w + lq * 4;
  const int uid0 = blockIdx.x * 2;
  const int ub0 = uid0 >> 7,        ut0 = (uid0 & 127) * 64;
  const int ub1 = (uid0 + 1) >> 7,  ut1 = ((uid0 + 1) & 127) * 64;

  // ---- residual chain lives in registers for the whole stack ----
  f32x4 xres[2][4];
  #pragma unroll
  for (int n = 0; n < 4; ++n) {
    {
      const int tg = ut0 + n * 16 + lh;
      f32x4 h;
      #pragma unroll
      for (int r = 0; r < 4; ++r) h[r] = x[((size_t)(ub0 * NC + o0 + r)) * NT + tg];
      xres[0][n] = h;
    }
    {
      const int tg = ut1 + n * 16 + lh;
      f32x4 h;
      #pragma unroll
      for (int r = 0; r < 4; ++r) h[r] = x[((size_t)(ub1 * NC + o0 + r)) * NT + tg];
      xres[1][n] = h;
    }
  }

  cg::grid_group grid = cg::this_grid();
  const f32x4 fz = {0.f, 0.f, 0.f, 0.f};

  for (int layer = 0; layer < NLAYER; ++layer) {
    const int d = 1 << (layer < 10 ? layer : layer - 10);
    const short* xbin  = (layer & 1) ? xb_b : xb_a;
    short*       xbout = (layer & 1) ? xb_a : xb_b;

    // ---- stage XP tiles (XC comes from previous epilogue; layer 0 stages XC) ----
    #pragma unroll
    for (int u = 0; u < 2; ++u) {
      const int ubu = u ? ub1 : ub0;
      const int utu = u ? ut1 : ut0;
      char* XP = ldsX[2 * u + 1];
      const int off = w * 2048 + l * 16;
      if (layer == 0) {
        const char* bc = (const char*)xbin + ((size_t)(ubu * NT + utu)) * 256;
        gl_lds16(bc + off, ldsX[2 * u] + off);
        gl_lds16(bc + off + 1024, ldsX[2 * u] + off + 1024);
      }
      if (utu >= d) {
        const char* bp = (const char*)xbin + ((size_t)(ubu * NT + utu - d)) * 256;
        gl_lds16(bp + off, XP + off);
        gl_lds16(bp + off + 1024, XP + off + 1024);
      } else {
        const int row = tid >> 3, j8 = tid & 7;
        const int tp = utu + row - d;
        char* dst = XP + row * 256;
        if (tp >= 0) {
          const char* src = (const char*)xbin + ((size_t)(ubu * NT + tp)) * 256;
          *(bf16x8*)(dst + j8 * 16)       = *(const bf16x8*)(src + j8 * 16);
          *(bf16x8*)(dst + j8 * 16 + 128) = *(const bf16x8*)(src + j8 * 16 + 128);
        } else {
          bf16x8 z = {0, 0, 0, 0, 0, 0, 0, 0};
          *(bf16x8*)(dst + j8 * 16)       = z;
          *(bf16x8*)(dst + j8 * 16 + 128) = z;
        }
      }
    }
    __syncthreads();

    #pragma unroll
    for (int u = 0; u < 2; ++u) {
      const int ubu = u ? ub1 : ub0;
      const int utu = u ? ut1 : ut0;
      const char* XP = ldsX[2 * u + 1];
      const char* XC = ldsX[2 * u];

      // ---- GEMM1: z[256 x 64], k = tap*128 + c (tap0 -> XP, tap1 -> XC) ----
      f32x4 acc1[2][4];
      #pragma unroll
      for (int mi = 0; mi < 2; ++mi)
        #pragma unroll
        for (int n = 0; n < 4; ++n) acc1[mi][n] = fz;

      const short* wl = wcb + (size_t)layer * 65536;
      #pragma unroll
      for (int ks = 0; ks < 8; ++ks) {
        const bf16x8 a0 = *(const bf16x8*)(wl + (16 * w + lh) * 256 + ks * 32 + lq * 8);
        const bf16x8 a1 = *(const bf16x8*)(wl + (128 + 16 * w + lh) * 256 + ks * 32 + lq * 8);
        const char* base = (ks < 4) ? XP : XC;
        const int dd = (ks < 4) ? d : 0;
        #pragma unroll
        for (int n = 0; n < 4; ++n) {
          const int tt = n * 16 + lh;
          const int ci = ((ks & 3) * 4 + lq) ^ ((tt - dd) & 7);
          const bf16x8 bb = *(const bf16x8*)(base + tt * 256 + ci * 16);
          acc1[0][n] = mfma16(a0, bb, acc1[0][n]);
          acc1[1][n] = mfma16(a1, bb, acc1[1][n]);
        }
      }

      // ---- gate -> ldsG (bf16) ----
      {
        float ba[4], bs[4];
        #pragma unroll
        for (int r = 0; r < 4; ++r) {
          ba[r] = b_conv[layer * 256 + o0 + r];
          bs[r] = b_conv[layer * 256 + 128 + o0 + r];
        }
        #pragma unroll
        for (int n = 0; n < 4; ++n) {
          bf16x4 g4;
          #pragma unroll
          for (int r = 0; r < 4; ++r) {
            const float za = acc1[0][n][r] + ba[r];
            const float zb = acc1[1][n][r] + bs[r];
            const float th = 1.f - 2.f / (1.f + __expf(2.f * za));
            const float sg = 1.f / (1.f + __expf(-zb));
            g4[r] = f2b(th * sg);
          }
          const int tt = n * 16 + lh;
          *(bf16x4*)(ldsG + tt * GROWB + o0 * 2) = g4;
        }
      }
      __syncthreads();

      // ---- GEMM2: s[128 x 64] = Wout * G ----
      f32x4 acc2[4];
      #pragma unroll
      for (int n = 0; n < 4; ++n) acc2[n] = fz;
      const short* wol = wob + (size_t)layer * 16384;
      #pragma unroll
      for (int ks = 0; ks < 4; ++ks) {
        const bf16x8 a = *(const bf16x8*)(wol + (16 * w + lh) * 128 + ks * 32 + lq * 8);
        #pragma unroll
        for (int n = 0; n < 4; ++n) {
          const int tt = n * 16 + lh;
          const bf16x8 bb = *(const bf16x8*)(ldsG + tt * GROWB + ks * 64 + lq * 16);
          acc2[n] = mfma16(a, bb, acc2[n]);
        }
      }

      // ---- epilogue: skip W, residual in regs, xb W + local next-XC ds_write ----
      {
        const size_t XOFFS = (size_t)NB * NC * NT;
        float bo[4];
        #pragma unroll
        for (int r = 0; r < 4; ++r) bo[r] = b_out[layer * 128 + o0 + r];
        #pragma unroll
        for (int n = 0; n < 4; ++n) {
          const int tt = n * 16 + lh;
          const int tg = utu + tt;
          f32x4 s4;
          #pragma unroll
          for (int r = 0; r < 4; ++r) s4[r] = acc2[n][r] + bo[r];
          #pragma unroll
          for (int r = 0; r < 4; ++r)
            out[XOFFS + ((size_t)((layer * NB + ubu) * NC + o0 + r)) * NT + tg] = s4[r];
          f32x4 xn;
          #pragma unroll
          for (int r = 0; r < 4; ++r) xn[r] = xres[u][n][r] + s4[r];
          xres[u][n] = xn;
          if (layer != NLAYER - 1) {
            bf16x4 x4;
            #pragma unroll
            for (int r = 0; r < 4; ++r) x4[r] = f2b(xn[r]);
            const int ci = (o0 >> 3) ^ (tt & 7);
            *(bf16x4*)((char*)xbout + ((size_t)(ubu * NT + tg)) * 256 + ci * 16 + (o0 & 7) * 2) = x4;
            *(bf16x4*)(ldsX[2 * u] + tt * 256 + ci * 16 + (o0 & 7) * 2) = x4;
          } else {
            #pragma unroll
            for (int r = 0; r < 4; ++r)
              out[((size_t)(ubu * NC + o0 + r)) * NT + tg] = xn[r];
          }
        }
      }
      __syncthreads();
    }

    if (layer != NLAYER - 1) {
      __threadfence();
      grid.sync();
    }
  }
}

extern "C" void kernel_launch(void* const* d_in, const int* in_sizes, int n_in,
                              void* d_out, int out_size, void* d_ws, size_t ws_size,
                              hipStream_t stream) {
  const float* x      = (const float*)d_in[0];
  const float* w_conv = (const float*)d_in[1];
  const float* b_conv = (const float*)d_in[2];
  const float* w_out  = (const float*)d_in[3];
  const float* b_out  = (const float*)d_in[4];
  float* out = (float*)d_out;

  const size_t XTN = (size_t)NB * NT * NC;      // 4,194,304
  short* xb_a = (short*)d_ws;
  short* xb_b = xb_a + XTN;
  short* wcb  = xb_b + XTN;
  short* wob  = wcb + CONVN;

  pack_weights<<<(CONVN + WOUTN + 255) / 256, 256, 0, stream>>>(w_conv, w_out, wcb, wob);
  transpose_in<<<dim3(NT / 64, NC / 64, NB), 256, 0, stream>>>(x, xb_a);

  void* args[] = {(void*)&wcb, (void*)&b_conv, (void*)&wob, (void*)&b_out,
                  (void*)&x, (void*)&xb_a, (void*)&xb_b, (void*)&out};
  hipLaunchCooperativeKernel((void*)wavenet_persistent, dim3(256), dim3(512),
                             args, 0, stream);
}

// Round 5
// 381.569 us; speedup vs baseline: 4.5805x; 4.5805x over previous
//
#include <hip/hip_runtime.h>
#include <hip/hip_bf16.h>
#include <stdint.h>

using f32x4  = __attribute__((ext_vector_type(4))) float;
using bf16x8 = __attribute__((ext_vector_type(8))) short;
using bf16x4 = __attribute__((ext_vector_type(4))) short;

#define NB   4
#define NC   128
#define NT   8192
#define TL   64
#define NLAYER 20
#define GROWB 272
#define CONVN (NLAYER * 256 * 256)
#define WOUTN (NLAYER * 128 * 128)

__device__ __forceinline__ short f2b(float f) {
  union { float f; unsigned u; } v; v.f = f;
  unsigned r = v.u + 0x7FFFu + ((v.u >> 16) & 1u);   // RNE
  return (short)(r >> 16);
}

__device__ __forceinline__ float b2f(short s) {
  union { unsigned u; float f; } v;
  v.u = ((unsigned)(unsigned short)s) << 16;
  return v.f;
}

__device__ __forceinline__ f32x4 mfma16(bf16x8 a, bf16x8 b, f32x4 c) {
  return __builtin_amdgcn_mfma_f32_16x16x32_bf16(a, b, c, 0, 0, 0);
}

__device__ __forceinline__ void gl_lds16(const void* g, void* l) {
  __builtin_amdgcn_global_load_lds(
      (const __attribute__((address_space(1))) void*)g,
      (__attribute__((address_space(3))) void*)l, 16, 0, 0);
}

// x [NB][NC][NT] f32 -> xtb bf16 swizzled (256B rows, 16B groups XOR t&7)
__global__ void transpose_in(const float* __restrict__ x, short* __restrict__ xtb) {
  __shared__ float tile[64][65];
  const int t0 = blockIdx.x * 64;
  const int c0 = blockIdx.y * 64;
  const int b  = blockIdx.z;
  const int lane = threadIdx.x & 63;
  const int r4   = threadIdx.x >> 6;
  #pragma unroll
  for (int i = 0; i < 16; ++i) {
    const int cl = i * 4 + r4;
    tile[cl][lane] = x[((size_t)(b * NC + c0 + cl)) * NT + t0 + lane];
  }
  __syncthreads();
  #pragma unroll
  for (int i = 0; i < 16; ++i) {
    const int tr = i * 4 + r4;
    const float v = tile[lane][tr];
    const int t = t0 + tr, c = c0 + lane;
    const size_t rowB = ((size_t)(b * NT + t)) * 256;
    const int ci = (c >> 3) ^ (t & 7);
    *(short*)((char*)xtb + rowB + ci * 16 + (c & 7) * 2) = f2b(v);
  }
}

// pack weights to bf16, fragment-ordered: wcb[l][o][k] with k = tap*128 + c
__global__ void pack_weights(const float* __restrict__ w_conv,
                             const float* __restrict__ w_out,
                             short* __restrict__ wcb, short* __restrict__ wob) {
  const int idx = blockIdx.x * 256 + threadIdx.x;
  if (idx < CONVN) {
    const int k = idx & 255, o = (idx >> 8) & 255, lyr = idx >> 16;
    const int tap = k >> 7, c = k & 127;
    wcb[idx] = f2b(w_conv[(((size_t)lyr * 256 + o) * 128 + c) * 2 + tap]);
  } else if (idx < CONVN + WOUTN) {
    const int j = idx - CONVN;
    wob[j] = f2b(w_out[j]);
  }
}

__global__ __launch_bounds__(512, 4)
void wavenet_layer(const short* __restrict__ wcb,
                   const float* __restrict__ b_conv,
                   const short* __restrict__ wob,
                   const float* __restrict__ b_out,
                   const short* __restrict__ xbin,  // bf16 swizzled [b][t] 256B rows
                   short* __restrict__ xbout,
                   float* __restrict__ out,
                   int layer, int dil, int last)
{
  __shared__ char ldsXP[TL * 256];
  __shared__ char ldsXC[TL * 256];
  __shared__ char ldsG[TL * GROWB];

  const int tid = threadIdx.x;
  const int w   = tid >> 6;
  const int l   = tid & 63;
  const int lh  = l & 15;
  const int lq  = l >> 4;
  const int o0  = 16 * w + lq * 4;
  // XCD-aware swizzle: XCD k (bid%8) gets contiguous unit range k*64..k*64+63
  const int uid = (blockIdx.x & 7) * 64 + (blockIdx.x >> 3);
  const int b   = uid >> 7;
  const int t0  = (uid & 127) * 64;

  // ---- stage XC tile via global_load_lds ----
  {
    const char* xcg = (const char*)xbin + ((size_t)(b * NT + t0)) * 256;
    const int off = w * 2048 + l * 16;
    gl_lds16(xcg + off, ldsXC + off);
    gl_lds16(xcg + off + 1024, ldsXC + off + 1024);
  }
  // ---- stage XP tile ----
  if (t0 >= dil) {
    const char* xpg = (const char*)xbin + ((size_t)(b * NT + t0 - dil)) * 256;
    const int off = w * 2048 + l * 16;
    gl_lds16(xpg + off, ldsXP + off);
    gl_lds16(xpg + off + 1024, ldsXP + off + 1024);
  } else {
    const int row = tid >> 3, j8 = tid & 7;
    const int tp = t0 + row - dil;
    char* dst = ldsXP + row * 256;
    if (tp >= 0) {
      const char* src = (const char*)xbin + ((size_t)(b * NT + tp)) * 256;
      *(bf16x8*)(dst + j8 * 16)       = *(const bf16x8*)(src + j8 * 16);
      *(bf16x8*)(dst + j8 * 16 + 128) = *(const bf16x8*)(src + j8 * 16 + 128);
    } else {
      bf16x8 z = {0, 0, 0, 0, 0, 0, 0, 0};
      *(bf16x8*)(dst + j8 * 16)       = z;
      *(bf16x8*)(dst + j8 * 16 + 128) = z;
    }
  }
  __syncthreads();

  // ---- GEMM1: z[256 x TL], k = tap*128 + c; tap0 -> XP, tap1 -> XC ----
  const f32x4 fz = {0.f, 0.f, 0.f, 0.f};
  f32x4 acc1[2][4];
  #pragma unroll
  for (int mi = 0; mi < 2; ++mi)
    #pragma unroll
    for (int n = 0; n < 4; ++n) acc1[mi][n] = fz;

  const short* wl = wcb + (size_t)layer * 65536;
  #pragma unroll
  for (int ks = 0; ks < 8; ++ks) {
    const bf16x8 a0 = *(const bf16x8*)(wl + (16 * w + lh) * 256 + ks * 32 + lq * 8);
    const bf16x8 a1 = *(const bf16x8*)(wl + (128 + 16 * w + lh) * 256 + ks * 32 + lq * 8);
    const char* base = (ks < 4) ? ldsXP : ldsXC;
    const int dd = (ks < 4) ? dil : 0;
    #pragma unroll
    for (int n = 0; n < 4; ++n) {
      const int tt = n * 16 + lh;
      const int ci = ((ks & 3) * 4 + lq) ^ ((tt - dd) & 7);
      const bf16x8 bb = *(const bf16x8*)(base + tt * 256 + ci * 16);
      acc1[0][n] = mfma16(a0, bb, acc1[0][n]);
      acc1[1][n] = mfma16(a1, bb, acc1[1][n]);
    }
  }

  // ---- gate: g = tanh(z_a) * sigmoid(z_b) -> bf16 ldsG ----
  {
    float ba[4], bs[4];
    #pragma unroll
    for (int r = 0; r < 4; ++r) {
      ba[r] = b_conv[layer * 256 + o0 + r];
      bs[r] = b_conv[layer * 256 + 128 + o0 + r];
    }
    #pragma unroll
    for (int n = 0; n < 4; ++n) {
      bf16x4 g4;
      #pragma unroll
      for (int r = 0; r < 4; ++r) {
        const float za = acc1[0][n][r] + ba[r];
        const float zb = acc1[1][n][r] + bs[r];
        const float th = 1.f - 2.f / (1.f + __expf(2.f * za));
        const float sg = 1.f / (1.f + __expf(-zb));
        g4[r] = f2b(th * sg);
      }
      const int tt = n * 16 + lh;
      *(bf16x4*)(ldsG + tt * GROWB + o0 * 2) = g4;
    }
  }
  __syncthreads();

  // ---- GEMM2: s[128 x TL] = Wout * G ----
  f32x4 acc2[4];
  #pragma unroll
  for (int n = 0; n < 4; ++n) acc2[n] = fz;
  const short* wol = wob + (size_t)layer * 16384;
  #pragma unroll
  for (int ks = 0; ks < 4; ++ks) {
    const bf16x8 a = *(const bf16x8*)(wol + (16 * w + lh) * 128 + ks * 32 + lq * 8);
    #pragma unroll
    for (int n = 0; n < 4; ++n) {
      const int tt = n * 16 + lh;
      const bf16x8 bb = *(const bf16x8*)(ldsG + tt * GROWB + ks * 64 + lq * 16);
      acc2[n] = mfma16(a, bb, acc2[n]);
    }
  }

  // ---- epilogue: skip W; residual = s + bf16(XC from LDS); xb W ----
  {
    const size_t XOFFS = (size_t)NB * NC * NT;
    float bo[4];
    #pragma unroll
    for (int r = 0; r < 4; ++r) bo[r] = b_out[layer * 128 + o0 + r];
    #pragma unroll
    for (int n = 0; n < 4; ++n) {
      const int tt = n * 16 + lh;
      const int tg = t0 + tt;
      f32x4 s4;
      #pragma unroll
      for (int r = 0; r < 4; ++r) s4[r] = acc2[n][r] + bo[r];
      #pragma unroll
      for (int r = 0; r < 4; ++r)
        out[XOFFS + ((size_t)((layer * NB + b) * NC + o0 + r)) * NT + tg] = s4[r];
      // residual h from the XC LDS tile (bf16 chain)
      const int ci = (o0 >> 3) ^ (tt & 7);
      const bf16x4 h4 = *(const bf16x4*)(ldsXC + tt * 256 + ci * 16 + (o0 & 7) * 2);
      f32x4 xn;
      #pragma unroll
      for (int r = 0; r < 4; ++r) xn[r] = s4[r] + b2f(h4[r]);
      if (!last) {
        bf16x4 x4;
        #pragma unroll
        for (int r = 0; r < 4; ++r) x4[r] = f2b(xn[r]);
        *(bf16x4*)((char*)xbout + ((size_t)(b * NT + tg)) * 256 + ci * 16 + (o0 & 7) * 2) = x4;
      } else {
        #pragma unroll
        for (int r = 0; r < 4; ++r)
          out[((size_t)(b * NC + o0 + r)) * NT + tg] = xn[r];
      }
    }
  }
}

extern "C" void kernel_launch(void* const* d_in, const int* in_sizes, int n_in,
                              void* d_out, int out_size, void* d_ws, size_t ws_size,
                              hipStream_t stream) {
  const float* x      = (const float*)d_in[0];
  const float* w_conv = (const float*)d_in[1];
  const float* b_conv = (const float*)d_in[2];
  const float* w_out  = (const float*)d_in[3];
  const float* b_out  = (const float*)d_in[4];
  float* out = (float*)d_out;

  const size_t XTN = (size_t)NB * NT * NC;      // 4,194,304
  short* xb_a = (short*)d_ws;
  short* xb_b = xb_a + XTN;
  short* wcb  = xb_b + XTN;
  short* wob  = wcb + CONVN;

  pack_weights<<<(CONVN + WOUTN + 255) / 256, 256, 0, stream>>>(w_conv, w_out, wcb, wob);
  transpose_in<<<dim3(NT / 64, NC / 64, NB), 256, 0, stream>>>(x, xb_a);

  static const int dil[NLAYER] = {1, 2, 4, 8, 16, 32, 64, 128, 256, 512,
                                  1, 2, 4, 8, 16, 32, 64, 128, 256, 512};
  for (int i = 0; i < NLAYER; ++i) {
    const short* xbi = (i & 1) ? xb_b : xb_a;
    short*       xbo = (i & 1) ? xb_a : xb_b;
    wavenet_layer<<<dim3(512), 512, 0, stream>>>(
        wcb, b_conv, wob, b_out, xbi, xbo, out, i, dil[i],
        (i == NLAYER - 1) ? 1 : 0);
  }
}